// Round 1
// baseline (65.085 us; speedup 1.0000x reference)
//
#include <hip/hip_runtime.h>

// MQCNN quanvolution: inputs (16,3,32,32) f32, weights (16,3,16) f32,
// output (16,16,31,31) f32. One thread per (o, b, h, w); loop over c.
// 4-qubit statevector (16 floats) lives in registers; wire q stride = 8>>q.

#define HPW 961           // 31*31
#define NPATCH 15376      // 16*31*31

template<int STRIDE>
__device__ __forceinline__ void ry_s(float* s, float c, float sn) {
#pragma unroll
    for (int i = 0; i < 16; ++i) {
        if ((i & STRIDE) == 0) {
            float a = s[i], b = s[i + STRIDE];
            s[i]          = c * a - sn * b;
            s[i + STRIDE] = sn * a + c * b;
        }
    }
}

template<int CS, int TS>
__device__ __forceinline__ void cnot_s(float* s) {
#pragma unroll
    for (int i = 0; i < 16; ++i) {
        if ((i & CS) != 0 && (i & TS) == 0) {
            float t = s[i]; s[i] = s[i + TS]; s[i + TS] = t;
        }
    }
}

// wire->stride: w0=8, w1=4, w2=2, w3=1

__device__ __forceinline__ void circ_ran(float* s, const float* C, const float* S) {
    ry_s<8>(s, C[0], S[0]); ry_s<4>(s, C[1], S[1]); ry_s<2>(s, C[2], S[2]); ry_s<1>(s, C[3], S[3]);
    cnot_s<8,4>(s); cnot_s<2,1>(s);
    ry_s<8>(s, C[4], S[4]); ry_s<2>(s, C[5], S[5]);
    cnot_s<4,2>(s);
    ry_s<4>(s, C[6], S[6]);
}

__device__ __forceinline__ void circ_line(float* s, const float* C, const float* S) {
    ry_s<8>(s, C[0], S[0]); ry_s<4>(s, C[1], S[1]); ry_s<2>(s, C[2], S[2]); ry_s<1>(s, C[3], S[3]);
    cnot_s<8,4>(s); cnot_s<4,2>(s); cnot_s<2,1>(s);
    ry_s<4>(s, C[4], S[4]); ry_s<2>(s, C[5], S[5]); ry_s<1>(s, C[6], S[6]);
}

__device__ __forceinline__ void circ_ring(float* s, const float* C, const float* S) {
    ry_s<8>(s, C[0], S[0]); ry_s<4>(s, C[1], S[1]); ry_s<2>(s, C[2], S[2]); ry_s<1>(s, C[3], S[3]);
    cnot_s<8,4>(s); cnot_s<4,2>(s); cnot_s<2,1>(s); cnot_s<1,8>(s);
    ry_s<8>(s, C[4], S[4]); ry_s<4>(s, C[5], S[5]); ry_s<2>(s, C[6], S[6]); ry_s<1>(s, C[7], S[7]);
}

__device__ __forceinline__ void circ_doublering(float* s, const float* C, const float* S) {
#pragma unroll
    for (int L = 0; L < 2; ++L) {
        const int b = 8 * L;
        ry_s<8>(s, C[b+0], S[b+0]); ry_s<4>(s, C[b+1], S[b+1]); ry_s<2>(s, C[b+2], S[b+2]); ry_s<1>(s, C[b+3], S[b+3]);
        cnot_s<8,4>(s); cnot_s<4,2>(s); cnot_s<2,1>(s); cnot_s<1,8>(s);
        ry_s<8>(s, C[b+4], S[b+4]); ry_s<4>(s, C[b+5], S[b+5]); ry_s<2>(s, C[b+6], S[b+6]); ry_s<1>(s, C[b+7], S[b+7]);
        // reversed ring: (3,0),(2,3),(1,2),(0,1)
        cnot_s<1,8>(s); cnot_s<2,1>(s); cnot_s<4,2>(s); cnot_s<8,4>(s);
    }
}

__device__ __forceinline__ void circ_blockring(float* s, const float* C, const float* S) {
#pragma unroll
    for (int L = 0; L < 3; ++L) {
        const int b = 4 * L;
        ry_s<8>(s, C[b+0], S[b+0]); ry_s<4>(s, C[b+1], S[b+1]); ry_s<2>(s, C[b+2], S[b+2]); ry_s<1>(s, C[b+3], S[b+3]);
        // (0,1),(2,3),(1,2),(3,0)
        cnot_s<8,4>(s); cnot_s<2,1>(s); cnot_s<4,2>(s); cnot_s<1,8>(s);
    }
}

__global__ __launch_bounds__(256) void quanv_kernel(const float* __restrict__ in,
                                                    const float* __restrict__ wts,
                                                    float* __restrict__ out) {
    __shared__ float cw[48], sw[48];
    const int o = blockIdx.y;
    const int t = threadIdx.x;
    if (t < 48) {
        float sn, cs;
        __sincosf(0.5f * wts[o * 48 + t], &sn, &cs);
        cw[t] = cs; sw[t] = sn;
    }
    __syncthreads();

    const int pidx = blockIdx.x * 256 + t;
    if (pidx >= NPATCH) return;
    const int b   = pidx / HPW;
    const int rem = pidx - b * HPW;
    const int h   = rem / 31;
    const int w   = rem - h * 31;
    const int circ = o % 5;   // uniform per block

    float acc = 0.0f;
#pragma unroll
    for (int c = 0; c < 3; ++c) {
        const float* p = in + (((b * 3 + c) * 32) + h) * 32 + w;
        const float x0 = p[0], x1 = p[1], x2 = p[32], x3 = p[33];

        float s0, c0, s1, c1, s2, c2, s3, c3;
        __sincosf(0.5f * x0, &s0, &c0);
        __sincosf(0.5f * x1, &s1, &c1);
        __sincosf(0.5f * x2, &s2, &c2);
        __sincosf(0.5f * x3, &s3, &c3);

        // product state |psi> = a0 (x) a1 (x) a2 (x) a3 ; index = b0*8+b1*4+b2*2+b3
        const float m00 = c0 * c1, m01 = c0 * s1, m10 = s0 * c1, m11 = s0 * s1; // wires 0,1
        const float n00 = c2 * c3, n01 = c2 * s3, n10 = s2 * c3, n11 = s2 * s3; // wires 2,3
        float s[16];
        s[0]  = m00 * n00; s[1]  = m00 * n01; s[2]  = m00 * n10; s[3]  = m00 * n11;
        s[4]  = m01 * n00; s[5]  = m01 * n01; s[6]  = m01 * n10; s[7]  = m01 * n11;
        s[8]  = m10 * n00; s[9]  = m10 * n01; s[10] = m10 * n10; s[11] = m10 * n11;
        s[12] = m11 * n00; s[13] = m11 * n01; s[14] = m11 * n10; s[15] = m11 * n11;

        const float* C = cw + c * 16;
        const float* S = sw + c * 16;
        switch (circ) {
            case 0: circ_ran(s, C, S);        break;
            case 1: circ_line(s, C, S);       break;
            case 2: circ_ring(s, C, S);       break;
            case 3: circ_doublering(s, C, S); break;
            default: circ_blockring(s, C, S); break;
        }

        float e = 0.0f;
#pragma unroll
        for (int i = 0; i < 8; ++i)  e += s[i] * s[i];
#pragma unroll
        for (int i = 8; i < 16; ++i) e -= s[i] * s[i];
        acc += e;
    }

    out[((b * 16 + o) * 31 + h) * 31 + w] = acc;
}

extern "C" void kernel_launch(void* const* d_in, const int* in_sizes, int n_in,
                              void* d_out, int out_size, void* d_ws, size_t ws_size,
                              hipStream_t stream) {
    const float* in  = (const float*)d_in[0];
    const float* wts = (const float*)d_in[1];
    float* out = (float*)d_out;
    dim3 grid((NPATCH + 255) / 256, 16);
    quanv_kernel<<<grid, 256, 0, stream>>>(in, wts, out);
}

// Round 2
// 61.769 us; speedup vs baseline: 1.0537x; 1.0537x over previous
//
#include <hip/hip_runtime.h>

// MQCNN quanvolution: inputs (16,3,32,32) f32, weights (16,3,16) f32,
// output (16,16,31,31) f32. One thread per (o, patch); loop over c.
// 4-qubit statevector (16 floats) in registers; wire q stride = 8>>q.
//
// Algebraic reductions (all exact):
//  - embed RY(x_i) + first-layer RY(w_i) fuse to RY(x_i+w_i)  (same axis)
//  - backward causal cone of Z0 prunes trailing gates not reaching wire 0
//  - line: z = cos(x0+w0)  (Z commutes with CNOT control)
//  - ran:  z = cos(w4)cos(a0) - sin(w4)sin(a0)sin(a1)
//  - CNOTs are register renames (zero ALU)

#define HPW 961           // 31*31
#define NPATCH 15376      // 16*31*31

template<int STRIDE>
__device__ __forceinline__ void ry_s(float* s, float c, float sn) {
#pragma unroll
    for (int i = 0; i < 16; ++i) {
        if ((i & STRIDE) == 0) {
            float a = s[i], b = s[i + STRIDE];
            s[i]          = c * a - sn * b;
            s[i + STRIDE] = sn * a + c * b;
        }
    }
}

template<int CS, int TS>
__device__ __forceinline__ void cnot_s(float* s) {
#pragma unroll
    for (int i = 0; i < 16; ++i) {
        if ((i & CS) != 0 && (i & TS) == 0) {
            float t = s[i]; s[i] = s[i + TS]; s[i + TS] = t;
        }
    }
}

__device__ __forceinline__ void build16(float* s,
        float c0, float s0, float c1, float s1,
        float c2, float s2, float c3, float s3) {
    const float m00 = c0 * c1, m01 = c0 * s1, m10 = s0 * c1, m11 = s0 * s1;
    const float n00 = c2 * c3, n01 = c2 * s3, n10 = s2 * c3, n11 = s2 * s3;
    s[0]  = m00 * n00; s[1]  = m00 * n01; s[2]  = m00 * n10; s[3]  = m00 * n11;
    s[4]  = m01 * n00; s[5]  = m01 * n01; s[6]  = m01 * n10; s[7]  = m01 * n11;
    s[8]  = m10 * n00; s[9]  = m10 * n01; s[10] = m10 * n10; s[11] = m10 * n11;
    s[12] = m11 * n00; s[13] = m11 * n01; s[14] = m11 * n10; s[15] = m11 * n11;
}

__device__ __forceinline__ float expz0v(const float* s) {
    float e = 0.0f;
#pragma unroll
    for (int i = 0; i < 8; ++i)  e += s[i] * s[i];
#pragma unroll
    for (int i = 8; i < 16; ++i) e -= s[i] * s[i];
    return e;
}

__global__ __launch_bounds__(256) void quanv_kernel(const float* __restrict__ in,
                                                    const float* __restrict__ wts,
                                                    float* __restrict__ out) {
    const int o = blockIdx.y;                 // block-uniform
    const int t = threadIdx.x;
    const int pidx = blockIdx.x * 256 + t;
    if (pidx >= NPATCH) return;
    const int b   = pidx / HPW;
    const int rem = pidx - b * HPW;
    const int h   = rem / 31;
    const int w   = rem - h * 31;
    const int circ = o % 5;                   // uniform per block

    const float* W  = wts + o * 48;           // uniform -> s_load
    const float* p0 = in + ((b * 3) * 32 + h) * 32 + w;
    float acc = 0.0f;

    switch (circ) {
    case 0: { // ran: z = cos(w4)cos(a0) - sin(w4)sin(a0)sin(a1)
#pragma unroll
        for (int c = 0; c < 3; ++c) {
            const float* p  = p0 + c * 1024;
            const float* wc = W + c * 16;
            const float a0 = p[0] + wc[0];
            const float a1 = p[1] + wc[1];
            float s4, c4;  __sincosf(wc[4], &s4, &c4);
            float sa0, ca0; __sincosf(a0, &sa0, &ca0);
            const float sa1 = __sinf(a1);
            acc += c4 * ca0 - s4 * sa0 * sa1;
        }
    } break;
    case 1: { // line: z = cos(x0+w0)
#pragma unroll
        for (int c = 0; c < 3; ++c)
            acc += __cosf(p0[c * 1024] + W[c * 16]);
    } break;
    case 2: { // ring: product(a0..a3) -> ring CNOTs -> RY(w4,wire0) -> Z0
#pragma unroll
        for (int c = 0; c < 3; ++c) {
            const float* p  = p0 + c * 1024;
            const float* wc = W + c * 16;
            float c0,s0,c1,s1,c2,s2,c3,s3;
            __sincosf(0.5f * (p[0]  + wc[0]), &s0, &c0);
            __sincosf(0.5f * (p[1]  + wc[1]), &s1, &c1);
            __sincosf(0.5f * (p[32] + wc[2]), &s2, &c2);
            __sincosf(0.5f * (p[33] + wc[3]), &s3, &c3);
            float s[16]; build16(s, c0,s0,c1,s1,c2,s2,c3,s3);
            cnot_s<8,4>(s); cnot_s<4,2>(s); cnot_s<2,1>(s); cnot_s<1,8>(s);
            float sw, cw; __sincosf(0.5f * wc[4], &sw, &cw);
            ry_s<8>(s, cw, sw);
            acc += expz0v(s);
        }
    } break;
    case 3: { // doublering: 2 layers, 12 simulated RYs
#pragma unroll
        for (int c = 0; c < 3; ++c) {
            const float* p  = p0 + c * 1024;
            const float* wc = W + c * 16;
            float c0,s0,c1,s1,c2,s2,c3,s3;
            __sincosf(0.5f * (p[0]  + wc[0]), &s0, &c0);
            __sincosf(0.5f * (p[1]  + wc[1]), &s1, &c1);
            __sincosf(0.5f * (p[32] + wc[2]), &s2, &c2);
            __sincosf(0.5f * (p[33] + wc[3]), &s3, &c3);
            float s[16]; build16(s, c0,s0,c1,s1,c2,s2,c3,s3);
            // L0: ring, RY(w4..w7), reversed ring
            cnot_s<8,4>(s); cnot_s<4,2>(s); cnot_s<2,1>(s); cnot_s<1,8>(s);
            float sg, cg;
            __sincosf(0.5f * wc[4], &sg, &cg); ry_s<8>(s, cg, sg);
            __sincosf(0.5f * wc[5], &sg, &cg); ry_s<4>(s, cg, sg);
            __sincosf(0.5f * wc[6], &sg, &cg); ry_s<2>(s, cg, sg);
            __sincosf(0.5f * wc[7], &sg, &cg); ry_s<1>(s, cg, sg);
            cnot_s<1,8>(s); cnot_s<2,1>(s); cnot_s<4,2>(s); cnot_s<8,4>(s);
            // L1: RY(w8..w11), ring, RY(w12..w15), reversed ring
            __sincosf(0.5f * wc[8],  &sg, &cg); ry_s<8>(s, cg, sg);
            __sincosf(0.5f * wc[9],  &sg, &cg); ry_s<4>(s, cg, sg);
            __sincosf(0.5f * wc[10], &sg, &cg); ry_s<2>(s, cg, sg);
            __sincosf(0.5f * wc[11], &sg, &cg); ry_s<1>(s, cg, sg);
            cnot_s<8,4>(s); cnot_s<4,2>(s); cnot_s<2,1>(s); cnot_s<1,8>(s);
            __sincosf(0.5f * wc[12], &sg, &cg); ry_s<8>(s, cg, sg);
            __sincosf(0.5f * wc[13], &sg, &cg); ry_s<4>(s, cg, sg);
            __sincosf(0.5f * wc[14], &sg, &cg); ry_s<2>(s, cg, sg);
            __sincosf(0.5f * wc[15], &sg, &cg); ry_s<1>(s, cg, sg);
            cnot_s<1,8>(s); cnot_s<2,1>(s); cnot_s<4,2>(s); cnot_s<8,4>(s);
            acc += expz0v(s);
        }
    } break;
    default: { // blockring: 3 layers (first RY layer fused), 8 simulated RYs
#pragma unroll
        for (int c = 0; c < 3; ++c) {
            const float* p  = p0 + c * 1024;
            const float* wc = W + c * 16;
            float c0,s0,c1,s1,c2,s2,c3,s3;
            __sincosf(0.5f * (p[0]  + wc[0]), &s0, &c0);
            __sincosf(0.5f * (p[1]  + wc[1]), &s1, &c1);
            __sincosf(0.5f * (p[32] + wc[2]), &s2, &c2);
            __sincosf(0.5f * (p[33] + wc[3]), &s3, &c3);
            float s[16]; build16(s, c0,s0,c1,s1,c2,s2,c3,s3);
            // cnots: (0,1),(2,3),(1,2),(3,0)
            cnot_s<8,4>(s); cnot_s<2,1>(s); cnot_s<4,2>(s); cnot_s<1,8>(s);
            float sg, cg;
            __sincosf(0.5f * wc[4], &sg, &cg); ry_s<8>(s, cg, sg);
            __sincosf(0.5f * wc[5], &sg, &cg); ry_s<4>(s, cg, sg);
            __sincosf(0.5f * wc[6], &sg, &cg); ry_s<2>(s, cg, sg);
            __sincosf(0.5f * wc[7], &sg, &cg); ry_s<1>(s, cg, sg);
            cnot_s<8,4>(s); cnot_s<2,1>(s); cnot_s<4,2>(s); cnot_s<1,8>(s);
            __sincosf(0.5f * wc[8],  &sg, &cg); ry_s<8>(s, cg, sg);
            __sincosf(0.5f * wc[9],  &sg, &cg); ry_s<4>(s, cg, sg);
            __sincosf(0.5f * wc[10], &sg, &cg); ry_s<2>(s, cg, sg);
            __sincosf(0.5f * wc[11], &sg, &cg); ry_s<1>(s, cg, sg);
            cnot_s<8,4>(s); cnot_s<2,1>(s); cnot_s<4,2>(s); cnot_s<1,8>(s);
            acc += expz0v(s);
        }
    } break;
    }

    out[((b * 16 + o) * 31 + h) * 31 + w] = acc;
}

extern "C" void kernel_launch(void* const* d_in, const int* in_sizes, int n_in,
                              void* d_out, int out_size, void* d_ws, size_t ws_size,
                              hipStream_t stream) {
    const float* in  = (const float*)d_in[0];
    const float* wts = (const float*)d_in[1];
    float* out = (float*)d_out;
    dim3 grid((NPATCH + 255) / 256, 16);
    quanv_kernel<<<grid, 256, 0, stream>>>(in, wts, out);
}

// Round 3
// 60.791 us; speedup vs baseline: 1.0706x; 1.0161x over previous
//
#include <hip/hip_runtime.h>

// MQCNN quanvolution: inputs (16,3,32,32) f32, weights (16,3,16) f32,
// output (16,16,31,31) f32. One thread per (o, patch); loop over c.
// Statevector (16 floats) in registers; wire q stride = 8>>q.
//
// Exact algebraic reductions:
//  - embed RY(x) + first RY(w) fuse to RY(x+w)
//  - line: z = cos(a0)
//  - ran:  z = cos(w4)cos(a0) - sin(w4)sin(a0)sin(a1)
//  - ring: z = cos(w4)cos(a1)cos(a2)cos(a3) - sin(w4)sin(a0)sin(a1)
//    (Heisenberg pullback of Z0 through the ring CNOTs)
//  - doublering tail prune: drop RY(w13),RY(w14) + 3 tail CNOTs (keep cnot(3,0))
//  - blockring tail prune: drop RY(w9), cnot(0,1), cnot(1,2) in last layer
//  - block-uniform weight sincos staged in LDS (48 half-angle pairs)

#define HPW 961           // 31*31
#define NPATCH 15376      // 16*31*31

template<int STRIDE>
__device__ __forceinline__ void ry_s(float* s, float c, float sn) {
#pragma unroll
    for (int i = 0; i < 16; ++i) {
        if ((i & STRIDE) == 0) {
            float a = s[i], b = s[i + STRIDE];
            s[i]          = c * a - sn * b;
            s[i + STRIDE] = sn * a + c * b;
        }
    }
}

template<int STRIDE>
__device__ __forceinline__ void ry_lds(float* s, float2 cs) {
    ry_s<STRIDE>(s, cs.x, cs.y);
}

template<int CS, int TS>
__device__ __forceinline__ void cnot_s(float* s) {
#pragma unroll
    for (int i = 0; i < 16; ++i) {
        if ((i & CS) != 0 && (i & TS) == 0) {
            float t = s[i]; s[i] = s[i + TS]; s[i + TS] = t;
        }
    }
}

__device__ __forceinline__ void build16(float* s,
        float c0, float s0, float c1, float s1,
        float c2, float s2, float c3, float s3) {
    const float m00 = c0 * c1, m01 = c0 * s1, m10 = s0 * c1, m11 = s0 * s1;
    const float n00 = c2 * c3, n01 = c2 * s3, n10 = s2 * c3, n11 = s2 * s3;
    s[0]  = m00 * n00; s[1]  = m00 * n01; s[2]  = m00 * n10; s[3]  = m00 * n11;
    s[4]  = m01 * n00; s[5]  = m01 * n01; s[6]  = m01 * n10; s[7]  = m01 * n11;
    s[8]  = m10 * n00; s[9]  = m10 * n01; s[10] = m10 * n10; s[11] = m10 * n11;
    s[12] = m11 * n00; s[13] = m11 * n01; s[14] = m11 * n10; s[15] = m11 * n11;
}

__device__ __forceinline__ float expz0v(const float* s) {
    float e = 0.0f;
#pragma unroll
    for (int i = 0; i < 8; ++i)  e = fmaf(s[i], s[i], e);
#pragma unroll
    for (int i = 8; i < 16; ++i) e = fmaf(-s[i], s[i], e);
    return e;
}

__global__ __launch_bounds__(256) void quanv_kernel(const float* __restrict__ in,
                                                    const float* __restrict__ wts,
                                                    float* __restrict__ out) {
    __shared__ float2 wcs[48];            // half-angle {cos, sin} of weights
    const int o = blockIdx.y;             // block-uniform
    const int t = threadIdx.x;
    const float* W = wts + o * 48;        // uniform -> s_load

    if (t < 48) {
        float sn, cs;
        __sincosf(0.5f * W[t], &sn, &cs);
        wcs[t] = make_float2(cs, sn);
    }
    __syncthreads();

    const int pidx = blockIdx.x * 256 + t;
    if (pidx >= NPATCH) return;
    const int b   = pidx / HPW;
    const int rem = pidx - b * HPW;
    const int h   = rem / 31;
    const int w   = rem - h * 31;
    const int circ = o % 5;               // uniform per block

    const float* p0 = in + ((b * 3) * 32 + h) * 32 + w;
    float acc = 0.0f;

    switch (circ) {
    case 0: { // ran: z = cos(w4)cos(a0) - sin(w4)sin(a0)sin(a1)
#pragma unroll
        for (int c = 0; c < 3; ++c) {
            const float* p  = p0 + c * 1024;
            const float* wc = W + c * 16;
            const float2 h4 = wcs[c * 16 + 4];
            const float cf = fmaf(-2.0f * h4.y, h4.y, 1.0f);  // cos w4
            const float sf = 2.0f * h4.x * h4.y;              // sin w4
            float sa0, ca0; __sincosf(p[0] + wc[0], &sa0, &ca0);
            const float sa1 = __sinf(p[1] + wc[1]);
            acc += cf * ca0 - sf * sa0 * sa1;
        }
    } break;
    case 1: { // line: z = cos(a0)
#pragma unroll
        for (int c = 0; c < 3; ++c)
            acc += __cosf(p0[c * 1024] + W[c * 16]);
    } break;
    case 2: { // ring: z = cos(w4)ca1*ca2*ca3 - sin(w4)sa0*sa1
#pragma unroll
        for (int c = 0; c < 3; ++c) {
            const float* p  = p0 + c * 1024;
            const float* wc = W + c * 16;
            const float2 h4 = wcs[c * 16 + 4];
            const float cf = fmaf(-2.0f * h4.y, h4.y, 1.0f);
            const float sf = 2.0f * h4.x * h4.y;
            const float sa0 = __sinf(p[0] + wc[0]);
            float sa1, ca1; __sincosf(p[1] + wc[1], &sa1, &ca1);
            const float ca2 = __cosf(p[32] + wc[2]);
            const float ca3 = __cosf(p[33] + wc[3]);
            acc += cf * ca1 * ca2 * ca3 - sf * sa0 * sa1;
        }
    } break;
    case 3: { // doublering (tail-pruned): 10 weight RYs per c
#pragma unroll
        for (int c = 0; c < 3; ++c) {
            const float* p  = p0 + c * 1024;
            const float* wc = W + c * 16;
            const float2* g = wcs + c * 16;
            float c0,s0,c1,s1,c2,s2,c3,s3;
            __sincosf(0.5f * (p[0]  + wc[0]), &s0, &c0);
            __sincosf(0.5f * (p[1]  + wc[1]), &s1, &c1);
            __sincosf(0.5f * (p[32] + wc[2]), &s2, &c2);
            __sincosf(0.5f * (p[33] + wc[3]), &s3, &c3);
            float s[16]; build16(s, c0,s0,c1,s1,c2,s2,c3,s3);
            // L0: ring
            cnot_s<8,4>(s); cnot_s<4,2>(s); cnot_s<2,1>(s); cnot_s<1,8>(s);
            ry_lds<8>(s, g[4]); ry_lds<4>(s, g[5]); ry_lds<2>(s, g[6]); ry_lds<1>(s, g[7]);
            // reversed ring
            cnot_s<1,8>(s); cnot_s<2,1>(s); cnot_s<4,2>(s); cnot_s<8,4>(s);
            // L1
            ry_lds<8>(s, g[8]); ry_lds<4>(s, g[9]); ry_lds<2>(s, g[10]); ry_lds<1>(s, g[11]);
            cnot_s<8,4>(s); cnot_s<4,2>(s); cnot_s<2,1>(s); cnot_s<1,8>(s);
            ry_lds<8>(s, g[12]); ry_lds<1>(s, g[15]);   // w13,w14 pruned
            cnot_s<1,8>(s);                              // only cnot(3,0) survives
            acc += expz0v(s);
        }
    } break;
    default: { // blockring (tail-pruned): 7 weight RYs per c
#pragma unroll
        for (int c = 0; c < 3; ++c) {
            const float* p  = p0 + c * 1024;
            const float* wc = W + c * 16;
            const float2* g = wcs + c * 16;
            float c0,s0,c1,s1,c2,s2,c3,s3;
            __sincosf(0.5f * (p[0]  + wc[0]), &s0, &c0);
            __sincosf(0.5f * (p[1]  + wc[1]), &s1, &c1);
            __sincosf(0.5f * (p[32] + wc[2]), &s2, &c2);
            __sincosf(0.5f * (p[33] + wc[3]), &s3, &c3);
            float s[16]; build16(s, c0,s0,c1,s1,c2,s2,c3,s3);
            // L0 cnots: (0,1),(2,3),(1,2),(3,0)
            cnot_s<8,4>(s); cnot_s<2,1>(s); cnot_s<4,2>(s); cnot_s<1,8>(s);
            ry_lds<8>(s, g[4]); ry_lds<4>(s, g[5]); ry_lds<2>(s, g[6]); ry_lds<1>(s, g[7]);
            // L1 cnots
            cnot_s<8,4>(s); cnot_s<2,1>(s); cnot_s<4,2>(s); cnot_s<1,8>(s);
            // L2: RY(w9,wire1) pruned; cnot(0,1),(1,2) pruned
            ry_lds<8>(s, g[8]); ry_lds<2>(s, g[10]); ry_lds<1>(s, g[11]);
            cnot_s<2,1>(s); cnot_s<1,8>(s);
            acc += expz0v(s);
        }
    } break;
    }

    out[((b * 16 + o) * 31 + h) * 31 + w] = acc;
}

extern "C" void kernel_launch(void* const* d_in, const int* in_sizes, int n_in,
                              void* d_out, int out_size, void* d_ws, size_t ws_size,
                              hipStream_t stream) {
    const float* in  = (const float*)d_in[0];
    const float* wts = (const float*)d_in[1];
    float* out = (float*)d_out;
    dim3 grid((NPATCH + 255) / 256, 16);
    quanv_kernel<<<grid, 256, 0, stream>>>(in, wts, out);
}